// Round 8
// baseline (581.306 us; speedup 1.0000x reference)
//
#include <hip/hip_runtime.h>
#include <hip/hip_fp16.h>

#define N_NODES    100000
#define N_EDGES    3200000
#define IN_DIM     128
#define EMB        32
#define NUM_GRAPHS 256

#define EDGE_BLOCKS 1563     // ceil(N_EDGES/4/512): int4 per thread
#define STILE       1024     // scan tile (elements per scan block)
#define SBLK        98       // ceil(N_NODES / STILE)
#define XW_BLOCKS   1563     // ceil(N_NODES / 64)

typedef _Float16 half8 __attribute__((ext_vector_type(8)));
typedef float floatx4 __attribute__((ext_vector_type(4)));
typedef int intx4 __attribute__((ext_vector_type(4)));   // vector type -> NT builtin ok

// ---------------------------------------------------------------------------
// k_deg: per-node degree histogram via direct global atomics. 3.2M atomics
// over 100K counters = max chain depth ~32 (R0's disaster was depth 3200 on
// 1024 coarse counters — depth, not atomic count, is what kills). NT loads:
// the edge stream must not evict L2-resident counters.
// ---------------------------------------------------------------------------
__global__ __launch_bounds__(512) void k_deg(const int* __restrict__ ei,
                                             int* __restrict__ deg) {
    int idx = blockIdx.x * 512 + threadIdx.x;
    int e = idx * 4;
    if (e < N_EDGES) {   // N_EDGES % 4 == 0: int4 always full
        intx4 d4 = __builtin_nontemporal_load((const intx4*)(ei + N_EDGES + e));
        atomicAdd(&deg[d4.x], 1);
        atomicAdd(&deg[d4.y], 1);
        atomicAdd(&deg[d4.z], 1);
        atomicAdd(&deg[d4.w], 1);
    }
}

// ---------------------------------------------------------------------------
// k_sa: per-tile degree sums (98 blocks x 256 thr, 4 elems/thr).
// ---------------------------------------------------------------------------
__global__ __launch_bounds__(256) void k_sa(const int* __restrict__ deg,
                                            int* __restrict__ tsum) {
    __shared__ int red[256];
    int b = blockIdx.x, t = threadIdx.x;
    int base = b * STILE + t * 4;
    int s = 0;
#pragma unroll
    for (int q = 0; q < 4; ++q) {
        int i = base + q;
        if (i < N_NODES) s += deg[i];
    }
    red[t] = s;
    __syncthreads();
    for (int off = 128; off; off >>= 1) {
        if (t < off) red[t] += red[t + off];
        __syncthreads();
    }
    if (t == 0) tsum[b] = red[0];
}

// ---------------------------------------------------------------------------
// k_sb: blocks 0..97 — exclusive scan (tile offset via redundant small prefix
// of tsum, k_mid trick) -> rowstart + cur (placement cursors) + dinv.
// Block 98 — aux: zero sums, per-graph counts, rowstart[N].
// ---------------------------------------------------------------------------
__global__ __launch_bounds__(256) void k_sb(const int* __restrict__ deg,
                                            const int* __restrict__ tsum,
                                            int* __restrict__ rowstart,
                                            int* __restrict__ cur,
                                            float* __restrict__ dinv,
                                            const int* __restrict__ batch,
                                            float* __restrict__ sums,
                                            float* __restrict__ counts) {
    int b = blockIdx.x, t = threadIdx.x;
    if (b == SBLK) {
        for (int i = t; i < NUM_GRAPHS * EMB; i += 256) sums[i] = 0.f;
        if (t < NUM_GRAPHS) {
            int lo = 0, hi = N_NODES;
            while (lo < hi) { int mid = (lo + hi) >> 1; if (batch[mid] < t) lo = mid + 1; else hi = mid; }
            int a = lo;
            lo = 0; hi = N_NODES;
            int g1 = t + 1;
            while (lo < hi) { int mid = (lo + hi) >> 1; if (batch[mid] < g1) lo = mid + 1; else hi = mid; }
            counts[t] = (float)(lo - a);
        }
        if (t == 0) rowstart[N_NODES] = N_EDGES;
        return;
    }
    __shared__ int pre[128];
    __shared__ int ts2[256];
    __shared__ int off_s;
    if (t < SBLK) pre[t] = tsum[t];
    int base = b * STILE + t * 4;
    int d[4]; int ssum = 0;
#pragma unroll
    for (int q = 0; q < 4; ++q) {
        int i = base + q;
        d[q] = (i < N_NODES) ? deg[i] : 0;
        ssum += d[q];
    }
    __syncthreads();
    if (t == 0) { int o = 0; for (int k = 0; k < b; ++k) o += pre[k]; off_s = o; }
    ts2[t] = ssum;
    __syncthreads();
    for (int off = 1; off < 256; off <<= 1) {
        int u = (t >= off) ? ts2[t - off] : 0;
        __syncthreads();
        ts2[t] += u;
        __syncthreads();
    }
    int run = off_s + ts2[t] - ssum;
#pragma unroll
    for (int q = 0; q < 4; ++q) {
        int i = base + q;
        if (i < N_NODES) {
            rowstart[i] = run;
            cur[i] = run;
            dinv[i] = rsqrtf((float)d[q] + 1.0f);
        }
        run += d[q];
    }
}

// ---------------------------------------------------------------------------
// k_place: single-pass placement. pos = atomicAdd(&cur[dst]); edge_src[pos]=s.
// No reservation chain (100K cursors), full occupancy. Scattered 4B writes:
// ~5x sector amp (R1 measured 67-77MB) = ~11us of BW — cheaper than the old
// fill+fill2 two-level sort it replaces. NT loads keep L2 for cur + merging.
// ---------------------------------------------------------------------------
__global__ __launch_bounds__(512) void k_place(const int* __restrict__ ei,
                                               int* __restrict__ cur,
                                               int* __restrict__ edge_src) {
    int idx = blockIdx.x * 512 + threadIdx.x;
    int e = idx * 4;
    if (e < N_EDGES) {
        intx4 s4 = __builtin_nontemporal_load((const intx4*)(ei + e));
        intx4 d4 = __builtin_nontemporal_load((const intx4*)(ei + N_EDGES + e));
        int p0 = atomicAdd(&cur[d4.x], 1);
        int p1 = atomicAdd(&cur[d4.y], 1);
        int p2 = atomicAdd(&cur[d4.z], 1);
        int p3 = atomicAdd(&cur[d4.w], 1);
        edge_src[p0] = s4.x;
        edge_src[p1] = s4.y;
        edge_src[p2] = s4.z;
        edge_src[p3] = s4.w;
    }
}

// ---------------------------------------------------------------------------
// xw = (x @ W1) * dinv[row] -> fp16 via MFMA 16x16x32_f16 (one wave = 16
// rows). Interleaved [N][32] output (plane splits regressed: R4 concurrent,
// R7 temporal — neither achieved L2 residency worth the extra pass).
// ---------------------------------------------------------------------------
__global__ __launch_bounds__(256) void k_xw(const float* __restrict__ x,
                                            const float* __restrict__ W1,
                                            const float* __restrict__ dinv,
                                            __half* __restrict__ xwh) {
    __shared__ _Float16 Wh[IN_DIM * (EMB + 1)];   // 8.25 KB, padded stride 33
    for (int i = threadIdx.x; i < IN_DIM * EMB; i += 256)
        Wh[(i >> 5) * (EMB + 1) + (i & 31)] = (_Float16)W1[i];
    __syncthreads();
    int wave = threadIdx.x >> 6;
    int lane = threadIdx.x & 63;
    int m = lane & 15, quad = lane >> 4;
    int row0 = (blockIdx.x * 4 + wave) * 16;
    if (row0 >= N_NODES) return;
    half8 bfrag[2][4];
#pragma unroll
    for (int nt = 0; nt < 2; ++nt)
#pragma unroll
        for (int ks = 0; ks < 4; ++ks)
#pragma unroll
            for (int j = 0; j < 8; ++j)
                bfrag[nt][ks][j] = Wh[(ks * 32 + quad * 8 + j) * (EMB + 1) + nt * 16 + m];
    const float* xr = x + (size_t)(row0 + m) * IN_DIM + quad * 8;
    floatx4 c0 = {0.f, 0.f, 0.f, 0.f}, c1 = {0.f, 0.f, 0.f, 0.f};
#pragma unroll
    for (int ks = 0; ks < 4; ++ks) {
        float4 a0 = *(const float4*)(xr + ks * 32);
        float4 a1 = *(const float4*)(xr + ks * 32 + 4);
        half8 af;
        af[0] = (_Float16)a0.x; af[1] = (_Float16)a0.y;
        af[2] = (_Float16)a0.z; af[3] = (_Float16)a0.w;
        af[4] = (_Float16)a1.x; af[5] = (_Float16)a1.y;
        af[6] = (_Float16)a1.z; af[7] = (_Float16)a1.w;
        c0 = __builtin_amdgcn_mfma_f32_16x16x32_f16(af, bfrag[0][ks], c0, 0, 0, 0);
        c1 = __builtin_amdgcn_mfma_f32_16x16x32_f16(af, bfrag[1][ks], c1, 0, 0, 0);
    }
#pragma unroll
    for (int r = 0; r < 4; ++r) {
        int ro = row0 + quad * 4 + r;
        float di = dinv[ro];
        xwh[(size_t)ro * EMB + m]      = __float2half(c0[r] * di);
        xwh[(size_t)ro * EMB + 16 + m] = __float2half(c1[r] * di);
    }
}

// ---------------------------------------------------------------------------
// Gather step: K edges, 8 lanes/node x half4 (8 B/lane -> 64 B/edge row).
// edge_src loads NONTEMPORAL: streamed once, must not evict the 6.4 MB xwh
// row table from L2.
// ---------------------------------------------------------------------------
template<int K>
__device__ __forceinline__ void gstep(const int* __restrict__ es,
                                      const float2* __restrict__ rows8,
                                      int cc, int e,
                                      float& a0, float& a1, float& a2, float& a3) {
    int s[K];
    float2 f[K];
#pragma unroll
    for (int k = 0; k < K; ++k) s[k] = __builtin_nontemporal_load(es + e + k);
#pragma unroll
    for (int k = 0; k < K; ++k) f[k] = rows8[(size_t)s[k] * 8 + cc];
#pragma unroll
    for (int k = 0; k < K; ++k) {
        float2 g01 = __half22float2(*(const __half2*)&f[k].x);
        float2 g23 = __half22float2(*(const __half2*)&f[k].y);
        a0 += g01.x; a1 += g01.y; a2 += g23.x; a3 += g23.y;
    }
}

// ---------------------------------------------------------------------------
// Fused gather: 8 lanes per node x half4. 32 nodes/block, 3125 blocks.
// Main 8-unroll + binary tail ladder. Epilogue: self-loop + tanh +
// sorted-batch pool.
// ---------------------------------------------------------------------------
__global__ __launch_bounds__(256) void k_gather(const __half* __restrict__ xws,
                                                const float* __restrict__ dinv,
                                                const int* __restrict__ rowstart,
                                                const int* __restrict__ edge_src,
                                                const int* __restrict__ batch,
                                                const float* __restrict__ b1,
                                                float* __restrict__ sums) {
    const float2* rows8 = (const float2*)xws;   // row = 8 x 8 B granules
    int grp = threadIdx.x >> 3;          // node slot 0..31
    int cc  = threadIdx.x & 7;           // half4 column group
    int i = blockIdx.x * 32 + grp;
    float di = dinv[i];
    int e0 = rowstart[i], e1 = rowstart[i + 1];
    float a0 = 0.f, a1 = 0.f, a2 = 0.f, a3 = 0.f;
    int e = e0;
    for (; e + 8 <= e1; e += 8) gstep<8>(edge_src, rows8, cc, e, a0, a1, a2, a3);
    if (e + 4 <= e1) { gstep<4>(edge_src, rows8, cc, e, a0, a1, a2, a3); e += 4; }
    if (e + 2 <= e1) { gstep<2>(edge_src, rows8, cc, e, a0, a1, a2, a3); e += 2; }
    if (e < e1)      { gstep<1>(edge_src, rows8, cc, e, a0, a1, a2, a3); }
    float2 fr = rows8[(size_t)i * 8 + cc];
    float2 fs01 = __half22float2(*(const __half2*)&fr.x);
    float2 fs23 = __half22float2(*(const __half2*)&fr.y);
    float4 bb = *(const float4*)(b1 + 4 * cc);
    float h0 = tanhf((a0 + fs01.x) * di + bb.x);
    float h1 = tanhf((a1 + fs01.y) * di + bb.y);
    float h2 = tanhf((a2 + fs23.x) * di + bb.z);
    float h3 = tanhf((a3 + fs23.y) * di + bb.w);

    __shared__ float hs[32][EMB];
    __shared__ int gb[32];
    *(float4*)&hs[grp][4 * cc] = make_float4(h0, h1, h2, h3);
    if (cc == 0) gb[grp] = batch[i];
    __syncthreads();
    if (threadIdx.x < 32) {
        int col = threadIdx.x;
        int rr = 0;
        while (rr < 32) {
            int g0 = gb[rr];
            float a = hs[rr][col];
            int r2 = rr + 1;
            while (r2 < 32 && gb[r2] == g0) { a += hs[r2][col]; ++r2; }
            atomicAdd(&sums[g0 * EMB + col], a);
            rr = r2;
        }
    }
}

// ---------------------------------------------------------------------------
// head: out[g] = [sums, means] @ Wout + bout
// ---------------------------------------------------------------------------
__global__ __launch_bounds__(64) void k_out(const float* __restrict__ sums,
                                            const float* __restrict__ counts,
                                            const float* __restrict__ Wout,
                                            const float* __restrict__ bout,
                                            float* __restrict__ out) {
    int g = blockIdx.x * 64 + threadIdx.x;
    if (g >= NUM_GRAPHS) return;
    float inv = 1.0f / fmaxf(counts[g], 1.0f);
    float acc = bout[0];
#pragma unroll
    for (int c = 0; c < EMB; ++c) {
        float s = sums[g * EMB + c];
        acc += s * Wout[c] + s * inv * Wout[EMB + c];
    }
    out[g] = acc;
}

extern "C" void kernel_launch(void* const* d_in, const int* in_sizes, int n_in,
                              void* d_out, int out_size, void* d_ws, size_t ws_size,
                              hipStream_t stream) {
    const float* x     = (const float*)d_in[0];
    const int*   ei    = (const int*)d_in[1];   // [2, E]
    const int*   batch = (const int*)d_in[2];   // [N], sorted
    const float* W1    = (const float*)d_in[3];
    const float* b1    = (const float*)d_in[4];
    const float* Wout  = (const float*)d_in[5];
    const float* bout  = (const float*)d_in[6];
    float* out = (float*)d_out;

    // workspace (~21 MB — recs/escr gone)
    char* ws = (char*)d_ws;
    __half* xwh     = (__half*)ws; ws += (size_t)N_NODES * EMB * sizeof(__half);  // 6.4 MB
    int* edge_src   = (int*)ws;    ws += (size_t)N_EDGES * sizeof(int);           // 12.8 MB
    int* rowstart   = (int*)ws;    ws += (size_t)(N_NODES + 4) * sizeof(int);     // 0.4 MB
    int* cur        = (int*)ws;    ws += (size_t)N_NODES * sizeof(int);           // 0.4 MB
    int* deg        = (int*)ws;    ws += (size_t)N_NODES * sizeof(int);           // 0.4 MB
    float* dinv     = (float*)ws;  ws += (size_t)N_NODES * sizeof(float);         // 0.4 MB
    int* tsum       = (int*)ws;    ws += 128 * sizeof(int);
    float* sums     = (float*)ws;  ws += (size_t)NUM_GRAPHS * EMB * sizeof(float);
    float* counts   = (float*)ws;

    hipMemsetAsync(deg, 0, (size_t)N_NODES * sizeof(int), stream);

    k_deg   <<<EDGE_BLOCKS, 512, 0, stream>>>(ei, deg);
    k_sa    <<<SBLK, 256, 0, stream>>>(deg, tsum);
    k_sb    <<<SBLK + 1, 256, 0, stream>>>(deg, tsum, rowstart, cur, dinv, batch, sums, counts);
    k_place <<<EDGE_BLOCKS, 512, 0, stream>>>(ei, cur, edge_src);
    k_xw    <<<XW_BLOCKS, 256, 0, stream>>>(x, W1, dinv, xwh);
    k_gather<<<N_NODES / 32, 256, 0, stream>>>(xwh, dinv, rowstart, edge_src, batch, b1, sums);
    k_out   <<<(NUM_GRAPHS + 63) / 64, 64, 0, stream>>>(sums, counts, Wout, bout, out);
}

// Round 9
// 216.287 us; speedup vs baseline: 2.6877x; 2.6877x over previous
//
#include <hip/hip_runtime.h>
#include <hip/hip_fp16.h>

#define N_NODES    100000
#define N_EDGES    3200000
#define IN_DIM     128
#define EMB        32
#define NUM_GRAPHS 256

#define FB         1024      // coarse buckets (782 used: bucket = dst >> 7)
#define NODES_PB   128       // nodes per bucket
#define NBUCKETS   782       // ceil(N_NODES / 128)
#define FB_B       512       // fill blocks
#define FB_EPB     6250      // 512 * 6250 == N_EDGES
#define NCHUNK     16        // block-dim prefix chunks (32 rows each)
#define CHROWS     32
#define XW_BLOCKS  1563      // ceil(N_NODES / 64)
#define CAP        5632      // fill2 LDS staging (mean 4092, +24 sigma)

typedef _Float16 half8 __attribute__((ext_vector_type(8)));
typedef float floatx4 __attribute__((ext_vector_type(4)));

// ---------------------------------------------------------------------------
// Per-block histogram of dst>>7, written as a coalesced private row (NO global
// atomics). bhist[FB_B][FB]. Rows are reused by k_fill (no second hist pass).
// NT loads: the edge stream is read-once; keep it out of L2.
// ---------------------------------------------------------------------------
__global__ __launch_bounds__(512) void k_hist(const int* __restrict__ ei,
                                              int* __restrict__ bhist) {
    __shared__ int h[FB];
    int t = threadIdx.x;
    for (int i = t; i < FB; i += 512) h[i] = 0;
    __syncthreads();
    int e0 = blockIdx.x * FB_EPB;
    for (int e = e0 + t; e < e0 + FB_EPB; e += 512)
        atomicAdd(&h[__builtin_nontemporal_load(ei + N_EDGES + e) >> 7], 1);
    __syncthreads();
    for (int i = t; i < FB; i += 512) bhist[blockIdx.x * FB + i] = h[i];
}

// ---------------------------------------------------------------------------
// Blocks 0..15: part[j][b] = sum of bhist rows in chunk j (32 rows).
// Block 16: zero sums + per-graph counts (folded aux work, saves a launch).
// ---------------------------------------------------------------------------
__global__ __launch_bounds__(512) void k_part(const int* __restrict__ bhist,
                                              int* __restrict__ part,
                                              const int* __restrict__ batch,
                                              float* __restrict__ sums,
                                              float* __restrict__ counts) {
    int j = blockIdx.x, t = threadIdx.x;
    if (j == NCHUNK) {
        for (int i = t; i < NUM_GRAPHS * EMB; i += 512) sums[i] = 0.f;
        if (t < NUM_GRAPHS) {
            int lo = 0, hi = N_NODES;
            while (lo < hi) { int mid = (lo + hi) >> 1; if (batch[mid] < t) lo = mid + 1; else hi = mid; }
            int a = lo;
            lo = 0; hi = N_NODES;
            int g1 = t + 1;
            while (lo < hi) { int mid = (lo + hi) >> 1; if (batch[mid] < g1) lo = mid + 1; else hi = mid; }
            counts[t] = (float)(lo - a);
        }
        return;
    }
    int row0 = j * CHROWS;
    for (int b = t; b < FB; b += 512) {
        int acc = 0;
#pragma unroll 8
        for (int i = 0; i < CHROWS; ++i) acc += bhist[(row0 + i) * FB + b];
        part[j * FB + b] = acc;
    }
}

// ---------------------------------------------------------------------------
// Each of 16 blocks redundantly computes bucket totals from part[] + the
// 1024-bucket exclusive scan (cbase), then writes the deterministic per-row
// bases bbase[row][b] for its own 32-row chunk. Block 0 also publishes cbase.
// ---------------------------------------------------------------------------
__global__ __launch_bounds__(1024) void k_mid(const int* __restrict__ bhist,
                                              const int* __restrict__ part,
                                              int* __restrict__ bbase,
                                              int* __restrict__ cbase) {
    __shared__ int ts[FB];
    int b = threadIdx.x;      // bucket
    int j = blockIdx.x;       // chunk (uniform)
    int tot = 0;
#pragma unroll
    for (int k = 0; k < NCHUNK; ++k) tot += part[k * FB + b];
    ts[b] = tot;
    __syncthreads();
    for (int off = 1; off < FB; off <<= 1) {
        int u = (b >= off) ? ts[b - off] : 0;
        __syncthreads();
        ts[b] += u;
        __syncthreads();
    }
    int cb = ts[b] - tot;     // exclusive over buckets
    if (j == 0) {
        cbase[b] = cb;
        if (b == 0) cbase[FB] = N_EDGES;
    }
    int run = cb;
    for (int k = 0; k < j; ++k) run += part[k * FB + b];   // L2-hot re-read
    int row0 = j * CHROWS;
    for (int i = 0; i < CHROWS; ++i) {
        int h = bhist[(row0 + i) * FB + b];
        bbase[(row0 + i) * FB + b] = run;
        run += h;
    }
}

// ---------------------------------------------------------------------------
// Scatter pass, LDS-staged counting sort (bucket granularity):
//   1. own bhist row -> in-block scan -> local bases
//   2. single edge pass: rec + global dest staged in LDS, bucket-sorted
//   3. write-out: consecutive lanes -> consecutive global addresses
// NT loads on the edge stream (read-once).
// ---------------------------------------------------------------------------
__global__ __launch_bounds__(512) void k_fill(const int* __restrict__ ei,
                                              const int* __restrict__ bhist,
                                              const int* __restrict__ bbase,
                                              unsigned int* __restrict__ recs) {
    __shared__ unsigned int staged[FB_EPB];   // 25000 B, bucket-sorted records
    __shared__ int dpos[FB_EPB];              // 25000 B, global destinations
    __shared__ int hd[FB];                    // hist, then delta = bbase - lbase
    __shared__ int cur[FB];                   // running local cursor
    __shared__ int ts[512];                   // scan scratch
    int t = threadIdx.x;
    int rowoff = blockIdx.x * FB;
    for (int i = t; i < FB; i += 512) hd[i] = bhist[rowoff + i];
    __syncthreads();
    int v0 = hd[2 * t], v1 = hd[2 * t + 1];
    int tot = v0 + v1;
    ts[t] = tot;
    __syncthreads();
    for (int off = 1; off < 512; off <<= 1) {
        int u = (t >= off) ? ts[t - off] : 0;
        __syncthreads();
        ts[t] += u;
        __syncthreads();
    }
    int lb0 = ts[t] - tot;     // exclusive local base, bucket 2t
    int lb1 = lb0 + v0;        // bucket 2t+1
    cur[2 * t] = lb0;
    cur[2 * t + 1] = lb1;
    hd[2 * t]     = bbase[rowoff + 2 * t]     - lb0;
    hd[2 * t + 1] = bbase[rowoff + 2 * t + 1] - lb1;
    __syncthreads();
    int e0 = blockIdx.x * FB_EPB;
    for (int e = e0 + t; e < e0 + FB_EPB; e += 512) {
        int s = __builtin_nontemporal_load(ei + e);
        int d = __builtin_nontemporal_load(ei + N_EDGES + e);
        int b = d >> 7;
        int lpos = atomicAdd(&cur[b], 1);
        staged[lpos] = ((unsigned int)(d & 127) << 24) | (unsigned int)s;
        dpos[lpos] = lpos + hd[b];
    }
    __syncthreads();
    for (int j = t; j < FB_EPB; j += 512)
        recs[dpos[j]] = staged[j];
}

// ---------------------------------------------------------------------------
// Fill2: one block per 128-node bucket (782 blocks, ~24 KB LDS -> 6/CU).
// LDS histogram of bucket's recs -> deg -> rowstart + dinv + cursors; staged
// counting sort emits edge_src.
// ---------------------------------------------------------------------------
__global__ __launch_bounds__(512) void k_fill2(const unsigned int* __restrict__ recs,
                                               const int* __restrict__ cbase,
                                               int* __restrict__ edge_src,
                                               int* __restrict__ rowstart,
                                               float* __restrict__ dinv) {
    __shared__ unsigned int lbuf[CAP];          // 22 KB
    __shared__ int h2[NODES_PB], cur2[NODES_PB], sc[NODES_PB];
    int t = threadIdx.x, b = blockIdx.x;
    if (t < NODES_PB) h2[t] = 0;
    __syncthreads();
    int seg0 = cbase[b];
    int cnt = cbase[b + 1] - seg0;
    for (int j = t; j < cnt; j += 512) {
        unsigned int r = recs[seg0 + j];
        if (j < CAP) lbuf[j] = r;
        atomicAdd(&h2[r >> 24], 1);
    }
    __syncthreads();
    int v = 0;
    if (t < NODES_PB) { v = h2[t]; sc[t] = v; }
    __syncthreads();
    for (int off = 1; off < NODES_PB; off <<= 1) {
        int u = 0;
        if (t < NODES_PB && t >= off) u = sc[t - off];
        __syncthreads();
        if (t < NODES_PB) sc[t] += u;
        __syncthreads();
    }
    int node0 = b << 7;
    if (t < NODES_PB) {
        int excl = sc[t] - v;
        cur2[t] = excl;
        int node = node0 + t;
        if (node < N_NODES) {
            rowstart[node] = seg0 + excl;
            dinv[node] = rsqrtf((float)v + 1.0f);
        }
    }
    if (b == 0 && t == 0) rowstart[N_NODES] = N_EDGES;
    __syncthreads();
    for (int j = t; j < cnt; j += 512) {
        unsigned int r = (j < CAP) ? lbuf[j] : recs[seg0 + j];
        int p = atomicAdd(&cur2[r >> 24], 1);
        edge_src[seg0 + p] = (int)(r & 0x00FFFFFF);
    }
}

// ---------------------------------------------------------------------------
// xw = (x @ W1) * dinv[row] -> fp16 via MFMA 16x16x32_f16 (one wave = 16
// rows). Interleaved [N][32] output (plane splits regressed: R4 concurrent,
// R7 temporal). Wh padded to stride 33 -> bfrag reads conflict-free.
// ---------------------------------------------------------------------------
__global__ __launch_bounds__(256) void k_xw(const float* __restrict__ x,
                                            const float* __restrict__ W1,
                                            const float* __restrict__ dinv,
                                            __half* __restrict__ xwh) {
    __shared__ _Float16 Wh[IN_DIM * (EMB + 1)];   // 8.25 KB, padded stride 33
    for (int i = threadIdx.x; i < IN_DIM * EMB; i += 256)
        Wh[(i >> 5) * (EMB + 1) + (i & 31)] = (_Float16)W1[i];
    __syncthreads();
    int wave = threadIdx.x >> 6;
    int lane = threadIdx.x & 63;
    int m = lane & 15, quad = lane >> 4;
    int row0 = (blockIdx.x * 4 + wave) * 16;
    if (row0 >= N_NODES) return;
    half8 bfrag[2][4];
#pragma unroll
    for (int nt = 0; nt < 2; ++nt)
#pragma unroll
        for (int ks = 0; ks < 4; ++ks)
#pragma unroll
            for (int j = 0; j < 8; ++j)
                bfrag[nt][ks][j] = Wh[(ks * 32 + quad * 8 + j) * (EMB + 1) + nt * 16 + m];
    const float* xr = x + (size_t)(row0 + m) * IN_DIM + quad * 8;
    floatx4 c0 = {0.f, 0.f, 0.f, 0.f}, c1 = {0.f, 0.f, 0.f, 0.f};
#pragma unroll
    for (int ks = 0; ks < 4; ++ks) {
        float4 a0 = *(const float4*)(xr + ks * 32);
        float4 a1 = *(const float4*)(xr + ks * 32 + 4);
        half8 af;
        af[0] = (_Float16)a0.x; af[1] = (_Float16)a0.y;
        af[2] = (_Float16)a0.z; af[3] = (_Float16)a0.w;
        af[4] = (_Float16)a1.x; af[5] = (_Float16)a1.y;
        af[6] = (_Float16)a1.z; af[7] = (_Float16)a1.w;
        c0 = __builtin_amdgcn_mfma_f32_16x16x32_f16(af, bfrag[0][ks], c0, 0, 0, 0);
        c1 = __builtin_amdgcn_mfma_f32_16x16x32_f16(af, bfrag[1][ks], c1, 0, 0, 0);
    }
#pragma unroll
    for (int r = 0; r < 4; ++r) {
        int ro = row0 + quad * 4 + r;
        float di = dinv[ro];
        xwh[(size_t)ro * EMB + m]      = __float2half(c0[r] * di);
        xwh[(size_t)ro * EMB + 16 + m] = __float2half(c1[r] * di);
    }
}

// ---------------------------------------------------------------------------
// Gather step helper: K parallel gathers (loads issued together, then summed).
// edge_src loads NONTEMPORAL: read-once stream must not evict the 6.4 MB xwh
// row table from L2.
// ---------------------------------------------------------------------------
template<int K>
__device__ __forceinline__ void gstep(const int* __restrict__ es,
                                      const __half2* __restrict__ rows,
                                      int cc, int e, float& a0, float& a1) {
    int s[K];
    float2 f[K];
#pragma unroll
    for (int k = 0; k < K; ++k) s[k] = __builtin_nontemporal_load(es + e + k);
#pragma unroll
    for (int k = 0; k < K; ++k) f[k] = __half22float2(rows[s[k] * 16 + cc]);
#pragma unroll
    for (int k = 0; k < K; ++k) { a0 += f[k].x; a1 += f[k].y; }
}

// ---------------------------------------------------------------------------
// Fused gather, half2: 16 lanes per node x 2 cols. Main 16-unroll + binary
// tail ladder. Epilogue: self-loop + tanh + sorted-batch pool.
// ---------------------------------------------------------------------------
__global__ __launch_bounds__(256) void k_gather(const __half* __restrict__ xws,
                                                const float* __restrict__ dinv,
                                                const int* __restrict__ rowstart,
                                                const int* __restrict__ edge_src,
                                                const int* __restrict__ batch,
                                                const float* __restrict__ b1,
                                                float* __restrict__ sums) {
    const __half2* rows = (const __half2*)xws;   // row stride = 16 half2
    int grp = threadIdx.x >> 4;          // node slot 0..15
    int cc  = threadIdx.x & 15;          // half2 column
    int i = blockIdx.x * 16 + grp;
    float di = dinv[i];
    int e0 = rowstart[i], e1 = rowstart[i + 1];
    float a0 = 0.f, a1 = 0.f;
    int e = e0;
    for (; e + 16 <= e1; e += 16) gstep<16>(edge_src, rows, cc, e, a0, a1);
    if (e + 8 <= e1) { gstep<8>(edge_src, rows, cc, e, a0, a1); e += 8; }
    if (e + 4 <= e1) { gstep<4>(edge_src, rows, cc, e, a0, a1); e += 4; }
    if (e + 2 <= e1) { gstep<2>(edge_src, rows, cc, e, a0, a1); e += 2; }
    if (e < e1)      { gstep<1>(edge_src, rows, cc, e, a0, a1); }
    float2 fs = __half22float2(rows[i * 16 + cc]);
    float2 bb = *(const float2*)(b1 + 2 * cc);
    float h0 = tanhf((a0 + fs.x) * di + bb.x);
    float h1 = tanhf((a1 + fs.y) * di + bb.y);

    __shared__ float hs[16][EMB];
    __shared__ int gb[16];
    *(float2*)&hs[grp][2 * cc] = make_float2(h0, h1);
    if (cc == 0) gb[grp] = batch[i];
    __syncthreads();
    if (threadIdx.x < 32) {
        int col = threadIdx.x;
        int rr = 0;
        while (rr < 16) {
            int g0 = gb[rr];
            float a = hs[rr][col];
            int r2 = rr + 1;
            while (r2 < 16 && gb[r2] == g0) { a += hs[r2][col]; ++r2; }
            atomicAdd(&sums[g0 * EMB + col], a);
            rr = r2;
        }
    }
}

// ---------------------------------------------------------------------------
// head: out[g] = [sums, means] @ Wout + bout
// ---------------------------------------------------------------------------
__global__ __launch_bounds__(64) void k_out(const float* __restrict__ sums,
                                            const float* __restrict__ counts,
                                            const float* __restrict__ Wout,
                                            const float* __restrict__ bout,
                                            float* __restrict__ out) {
    int g = blockIdx.x * 64 + threadIdx.x;
    if (g >= NUM_GRAPHS) return;
    float inv = 1.0f / fmaxf(counts[g], 1.0f);
    float acc = bout[0];
#pragma unroll
    for (int c = 0; c < EMB; ++c) {
        float s = sums[g * EMB + c];
        acc += s * Wout[c] + s * inv * Wout[EMB + c];
    }
    out[g] = acc;
}

extern "C" void kernel_launch(void* const* d_in, const int* in_sizes, int n_in,
                              void* d_out, int out_size, void* d_ws, size_t ws_size,
                              hipStream_t stream) {
    const float* x     = (const float*)d_in[0];
    const int*   ei    = (const int*)d_in[1];   // [2, E]
    const int*   batch = (const int*)d_in[2];   // [N], sorted
    const float* W1    = (const float*)d_in[3];
    const float* b1    = (const float*)d_in[4];
    const float* Wout  = (const float*)d_in[5];
    const float* bout  = (const float*)d_in[6];
    float* out = (float*)d_out;

    // workspace (~33 MB)
    char* ws = (char*)d_ws;
    __half* xwh        = (__half*)ws;       ws += (size_t)N_NODES * EMB * sizeof(__half);  // 6.4 MB
    unsigned int* recs = (unsigned int*)ws; ws += (size_t)N_EDGES * sizeof(int);           // 12.8 MB
    int*   edge_src    = (int*)ws;          ws += (size_t)N_EDGES * sizeof(int);           // 12.8 MB
    int*   rowstart    = (int*)ws;          ws += (size_t)(N_NODES + 4) * sizeof(int);     // 0.4 MB
    float* dinv        = (float*)ws;        ws += (size_t)N_NODES * sizeof(float);         // 0.4 MB
    int*   cbase       = (int*)ws;          ws += (FB + 2) * sizeof(int);
    float* sums        = (float*)ws;        ws += (size_t)NUM_GRAPHS * EMB * sizeof(float);
    float* counts      = (float*)ws;

    // Overlay the prefix-sum scratch inside edge_src: bhist (2 MB) + part
    // (64 KB) + bbase (2 MB) are dead before k_fill2 writes edge_src.
    int* bhist = edge_src;                       // [FB_B][FB]  2 MB
    int* part  = bhist + (size_t)FB_B * FB;      // [NCHUNK][FB] 64 KB
    int* bbase = part + (size_t)NCHUNK * FB;     // [FB_B][FB]  2 MB

    k_hist  <<<FB_B, 512, 0, stream>>>(ei, bhist);
    k_part  <<<NCHUNK + 1, 512, 0, stream>>>(bhist, part, batch, sums, counts);
    k_mid   <<<NCHUNK, 1024, 0, stream>>>(bhist, part, bbase, cbase);
    k_fill  <<<FB_B, 512, 0, stream>>>(ei, bhist, bbase, recs);
    k_fill2 <<<NBUCKETS, 512, 0, stream>>>(recs, cbase, edge_src, rowstart, dinv);
    k_xw    <<<XW_BLOCKS, 256, 0, stream>>>(x, W1, dinv, xwh);
    k_gather<<<N_NODES / 16, 256, 0, stream>>>(xwh, dinv, rowstart, edge_src, batch, b1, sums);
    k_out   <<<(NUM_GRAPHS + 63) / 64, 64, 0, stream>>>(sums, counts, Wout, bout, out);
}

// Round 10
// 201.007 us; speedup vs baseline: 2.8920x; 1.0760x over previous
//
#include <hip/hip_runtime.h>
#include <hip/hip_fp16.h>

#define N_NODES    100000
#define N_EDGES    3200000
#define IN_DIM     128
#define EMB        32
#define NUM_GRAPHS 256

#define FB         1024      // coarse buckets (782 used: bucket = dst >> 7)
#define NODES_PB   128       // nodes per bucket
#define NBUCKETS   782       // ceil(N_NODES / 128)
#define FB_B       512       // fill blocks
#define FB_EPB     6250      // 512 * 6250 == N_EDGES
#define NCHUNK     16        // block-dim prefix chunks (32 rows each)
#define CHROWS     32
#define XW_BLOCKS  1563      // ceil(N_NODES / 64)
#define CAP        5632      // fill2 LDS staging (mean 4092, +24 sigma)

typedef _Float16 half8 __attribute__((ext_vector_type(8)));
typedef float floatx4 __attribute__((ext_vector_type(4)));

// ---------------------------------------------------------------------------
// Per-block histogram of dst>>7, written as a coalesced private row (NO global
// atomics). bhist[FB_B][FB]. Rows are reused by k_fill (no second hist pass).
// ---------------------------------------------------------------------------
__global__ __launch_bounds__(512) void k_hist(const int* __restrict__ ei,
                                              int* __restrict__ bhist) {
    __shared__ int h[FB];
    int t = threadIdx.x;
    for (int i = t; i < FB; i += 512) h[i] = 0;
    __syncthreads();
    int e0 = blockIdx.x * FB_EPB;
    for (int e = e0 + t; e < e0 + FB_EPB; e += 512)
        atomicAdd(&h[ei[N_EDGES + e] >> 7], 1);
    __syncthreads();
    for (int i = t; i < FB; i += 512) bhist[blockIdx.x * FB + i] = h[i];
}

// ---------------------------------------------------------------------------
// Blocks 0..15: part[j][b] = sum of bhist rows in chunk j (32 rows).
// Block 16: zero sums + per-graph counts (folded aux work, saves a launch).
// ---------------------------------------------------------------------------
__global__ __launch_bounds__(512) void k_part(const int* __restrict__ bhist,
                                              int* __restrict__ part,
                                              const int* __restrict__ batch,
                                              float* __restrict__ sums,
                                              float* __restrict__ counts) {
    int j = blockIdx.x, t = threadIdx.x;
    if (j == NCHUNK) {
        for (int i = t; i < NUM_GRAPHS * EMB; i += 512) sums[i] = 0.f;
        if (t < NUM_GRAPHS) {
            int lo = 0, hi = N_NODES;
            while (lo < hi) { int mid = (lo + hi) >> 1; if (batch[mid] < t) lo = mid + 1; else hi = mid; }
            int a = lo;
            lo = 0; hi = N_NODES;
            int g1 = t + 1;
            while (lo < hi) { int mid = (lo + hi) >> 1; if (batch[mid] < g1) lo = mid + 1; else hi = mid; }
            counts[t] = (float)(lo - a);
        }
        return;
    }
    int row0 = j * CHROWS;
    for (int b = t; b < FB; b += 512) {
        int acc = 0;
#pragma unroll 8
        for (int i = 0; i < CHROWS; ++i) acc += bhist[(row0 + i) * FB + b];
        part[j * FB + b] = acc;
    }
}

// ---------------------------------------------------------------------------
// Each of 16 blocks redundantly computes bucket totals from part[] + the
// 1024-bucket exclusive scan (cbase), then writes the deterministic per-row
// bases bbase[row][b] for its own 32-row chunk. Block 0 also publishes cbase.
// ---------------------------------------------------------------------------
__global__ __launch_bounds__(1024) void k_mid(const int* __restrict__ bhist,
                                              const int* __restrict__ part,
                                              int* __restrict__ bbase,
                                              int* __restrict__ cbase) {
    __shared__ int ts[FB];
    int b = threadIdx.x;      // bucket
    int j = blockIdx.x;       // chunk (uniform)
    int tot = 0;
#pragma unroll
    for (int k = 0; k < NCHUNK; ++k) tot += part[k * FB + b];
    ts[b] = tot;
    __syncthreads();
    for (int off = 1; off < FB; off <<= 1) {
        int u = (b >= off) ? ts[b - off] : 0;
        __syncthreads();
        ts[b] += u;
        __syncthreads();
    }
    int cb = ts[b] - tot;     // exclusive over buckets
    if (j == 0) {
        cbase[b] = cb;
        if (b == 0) cbase[FB] = N_EDGES;
    }
    int run = cb;
    for (int k = 0; k < j; ++k) run += part[k * FB + b];   // L2-hot re-read
    int row0 = j * CHROWS;
    for (int i = 0; i < CHROWS; ++i) {
        int h = bhist[(row0 + i) * FB + b];
        bbase[(row0 + i) * FB + b] = run;
        run += h;
    }
}

// ---------------------------------------------------------------------------
// Scatter pass, LDS-staged counting sort (bucket granularity):
//   1. own bhist row -> in-block scan -> local bases
//   2. single edge pass: rec + global dest staged in LDS, bucket-sorted
//   3. write-out: consecutive lanes -> consecutive global addresses
// ---------------------------------------------------------------------------
__global__ __launch_bounds__(512) void k_fill(const int* __restrict__ ei,
                                              const int* __restrict__ bhist,
                                              const int* __restrict__ bbase,
                                              unsigned int* __restrict__ recs) {
    __shared__ unsigned int staged[FB_EPB];   // 25000 B, bucket-sorted records
    __shared__ int dpos[FB_EPB];              // 25000 B, global destinations
    __shared__ int hd[FB];                    // hist, then delta = bbase - lbase
    __shared__ int cur[FB];                   // running local cursor
    __shared__ int ts[512];                   // scan scratch
    int t = threadIdx.x;
    int rowoff = blockIdx.x * FB;
    for (int i = t; i < FB; i += 512) hd[i] = bhist[rowoff + i];
    __syncthreads();
    int v0 = hd[2 * t], v1 = hd[2 * t + 1];
    int tot = v0 + v1;
    ts[t] = tot;
    __syncthreads();
    for (int off = 1; off < 512; off <<= 1) {
        int u = (t >= off) ? ts[t - off] : 0;
        __syncthreads();
        ts[t] += u;
        __syncthreads();
    }
    int lb0 = ts[t] - tot;     // exclusive local base, bucket 2t
    int lb1 = lb0 + v0;        // bucket 2t+1
    cur[2 * t] = lb0;
    cur[2 * t + 1] = lb1;
    hd[2 * t]     = bbase[rowoff + 2 * t]     - lb0;
    hd[2 * t + 1] = bbase[rowoff + 2 * t + 1] - lb1;
    __syncthreads();
    int e0 = blockIdx.x * FB_EPB;
    for (int e = e0 + t; e < e0 + FB_EPB; e += 512) {
        int s = ei[e];
        int d = ei[N_EDGES + e];
        int b = d >> 7;
        int lpos = atomicAdd(&cur[b], 1);
        staged[lpos] = ((unsigned int)(d & 127) << 24) | (unsigned int)s;
        dpos[lpos] = lpos + hd[b];
    }
    __syncthreads();
    for (int j = t; j < FB_EPB; j += 512)
        recs[dpos[j]] = staged[j];
}

// ---------------------------------------------------------------------------
// Fill2: one block per 128-node bucket (782 blocks, ~24 KB LDS -> 6/CU).
// LDS histogram of bucket's recs -> deg -> rowstart + dinv + cursors; staged
// counting sort emits edge_src.
// ---------------------------------------------------------------------------
__global__ __launch_bounds__(512) void k_fill2(const unsigned int* __restrict__ recs,
                                               const int* __restrict__ cbase,
                                               int* __restrict__ edge_src,
                                               int* __restrict__ rowstart,
                                               float* __restrict__ dinv) {
    __shared__ unsigned int lbuf[CAP];          // 22 KB
    __shared__ int h2[NODES_PB], cur2[NODES_PB], sc[NODES_PB];
    int t = threadIdx.x, b = blockIdx.x;
    if (t < NODES_PB) h2[t] = 0;
    __syncthreads();
    int seg0 = cbase[b];
    int cnt = cbase[b + 1] - seg0;
    for (int j = t; j < cnt; j += 512) {
        unsigned int r = recs[seg0 + j];
        if (j < CAP) lbuf[j] = r;
        atomicAdd(&h2[r >> 24], 1);
    }
    __syncthreads();
    int v = 0;
    if (t < NODES_PB) { v = h2[t]; sc[t] = v; }
    __syncthreads();
    for (int off = 1; off < NODES_PB; off <<= 1) {
        int u = 0;
        if (t < NODES_PB && t >= off) u = sc[t - off];
        __syncthreads();
        if (t < NODES_PB) sc[t] += u;
        __syncthreads();
    }
    int node0 = b << 7;
    if (t < NODES_PB) {
        int excl = sc[t] - v;
        cur2[t] = excl;
        int node = node0 + t;
        if (node < N_NODES) {
            rowstart[node] = seg0 + excl;
            dinv[node] = rsqrtf((float)v + 1.0f);
        }
    }
    if (b == 0 && t == 0) rowstart[N_NODES] = N_EDGES;
    __syncthreads();
    for (int j = t; j < cnt; j += 512) {
        unsigned int r = (j < CAP) ? lbuf[j] : recs[seg0 + j];
        int p = atomicAdd(&cur2[r >> 24], 1);
        edge_src[seg0 + p] = (int)(r & 0x00FFFFFF);
    }
}

// ---------------------------------------------------------------------------
// xw = (x @ W1) * dinv[row] -> fp16 via MFMA 16x16x32_f16 (one wave = 16
// rows). Interleaved [N][32] output. Wh padded to stride 33 -> conflict-free.
// ---------------------------------------------------------------------------
__global__ __launch_bounds__(256) void k_xw(const float* __restrict__ x,
                                            const float* __restrict__ W1,
                                            const float* __restrict__ dinv,
                                            __half* __restrict__ xwh) {
    __shared__ _Float16 Wh[IN_DIM * (EMB + 1)];   // 8.25 KB, padded stride 33
    for (int i = threadIdx.x; i < IN_DIM * EMB; i += 256)
        Wh[(i >> 5) * (EMB + 1) + (i & 31)] = (_Float16)W1[i];
    __syncthreads();
    int wave = threadIdx.x >> 6;
    int lane = threadIdx.x & 63;
    int m = lane & 15, quad = lane >> 4;
    int row0 = (blockIdx.x * 4 + wave) * 16;
    if (row0 >= N_NODES) return;
    half8 bfrag[2][4];
#pragma unroll
    for (int nt = 0; nt < 2; ++nt)
#pragma unroll
        for (int ks = 0; ks < 4; ++ks)
#pragma unroll
            for (int j = 0; j < 8; ++j)
                bfrag[nt][ks][j] = Wh[(ks * 32 + quad * 8 + j) * (EMB + 1) + nt * 16 + m];
    const float* xr = x + (size_t)(row0 + m) * IN_DIM + quad * 8;
    floatx4 c0 = {0.f, 0.f, 0.f, 0.f}, c1 = {0.f, 0.f, 0.f, 0.f};
#pragma unroll
    for (int ks = 0; ks < 4; ++ks) {
        float4 a0 = *(const float4*)(xr + ks * 32);
        float4 a1 = *(const float4*)(xr + ks * 32 + 4);
        half8 af;
        af[0] = (_Float16)a0.x; af[1] = (_Float16)a0.y;
        af[2] = (_Float16)a0.z; af[3] = (_Float16)a0.w;
        af[4] = (_Float16)a1.x; af[5] = (_Float16)a1.y;
        af[6] = (_Float16)a1.z; af[7] = (_Float16)a1.w;
        c0 = __builtin_amdgcn_mfma_f32_16x16x32_f16(af, bfrag[0][ks], c0, 0, 0, 0);
        c1 = __builtin_amdgcn_mfma_f32_16x16x32_f16(af, bfrag[1][ks], c1, 0, 0, 0);
    }
#pragma unroll
    for (int r = 0; r < 4; ++r) {
        int ro = row0 + quad * 4 + r;
        float di = dinv[ro];
        xwh[(size_t)ro * EMB + m]      = __float2half(c0[r] * di);
        xwh[(size_t)ro * EMB + 16 + m] = __float2half(c1[r] * di);
    }
}

// ---------------------------------------------------------------------------
// Gather step helper: K parallel gathers (loads issued together, then summed)
// ---------------------------------------------------------------------------
template<int K>
__device__ __forceinline__ void gstep(const int* __restrict__ es,
                                      const __half2* __restrict__ rows,
                                      int cc, int e, float& a0, float& a1) {
    int s[K];
    float2 f[K];
#pragma unroll
    for (int k = 0; k < K; ++k) s[k] = es[e + k];
#pragma unroll
    for (int k = 0; k < K; ++k) f[k] = __half22float2(rows[s[k] * 16 + cc]);
#pragma unroll
    for (int k = 0; k < K; ++k) { a0 += f[k].x; a1 += f[k].y; }
}

// ---------------------------------------------------------------------------
// Fused gather, half2: 16 lanes per node x 2 cols. Main 16-unroll + binary
// tail ladder. Epilogue: self-loop + tanh + sorted-batch pool.
// ---------------------------------------------------------------------------
__global__ __launch_bounds__(256) void k_gather(const __half* __restrict__ xws,
                                                const float* __restrict__ dinv,
                                                const int* __restrict__ rowstart,
                                                const int* __restrict__ edge_src,
                                                const int* __restrict__ batch,
                                                const float* __restrict__ b1,
                                                float* __restrict__ sums) {
    const __half2* rows = (const __half2*)xws;   // row stride = 16 half2
    int grp = threadIdx.x >> 4;          // node slot 0..15
    int cc  = threadIdx.x & 15;          // half2 column
    int i = blockIdx.x * 16 + grp;
    float di = dinv[i];
    int e0 = rowstart[i], e1 = rowstart[i + 1];
    float a0 = 0.f, a1 = 0.f;
    int e = e0;
    for (; e + 16 <= e1; e += 16) gstep<16>(edge_src, rows, cc, e, a0, a1);
    if (e + 8 <= e1) { gstep<8>(edge_src, rows, cc, e, a0, a1); e += 8; }
    if (e + 4 <= e1) { gstep<4>(edge_src, rows, cc, e, a0, a1); e += 4; }
    if (e + 2 <= e1) { gstep<2>(edge_src, rows, cc, e, a0, a1); e += 2; }
    if (e < e1)      { gstep<1>(edge_src, rows, cc, e, a0, a1); }
    float2 fs = __half22float2(rows[i * 16 + cc]);
    float2 bb = *(const float2*)(b1 + 2 * cc);
    float h0 = tanhf((a0 + fs.x) * di + bb.x);
    float h1 = tanhf((a1 + fs.y) * di + bb.y);

    __shared__ float hs[16][EMB];
    __shared__ int gb[16];
    *(float2*)&hs[grp][2 * cc] = make_float2(h0, h1);
    if (cc == 0) gb[grp] = batch[i];
    __syncthreads();
    if (threadIdx.x < 32) {
        int col = threadIdx.x;
        int rr = 0;
        while (rr < 16) {
            int g0 = gb[rr];
            float a = hs[rr][col];
            int r2 = rr + 1;
            while (r2 < 16 && gb[r2] == g0) { a += hs[r2][col]; ++r2; }
            atomicAdd(&sums[g0 * EMB + col], a);
            rr = r2;
        }
    }
}

// ---------------------------------------------------------------------------
// head: out[g] = [sums, means] @ Wout + bout
// ---------------------------------------------------------------------------
__global__ __launch_bounds__(64) void k_out(const float* __restrict__ sums,
                                            const float* __restrict__ counts,
                                            const float* __restrict__ Wout,
                                            const float* __restrict__ bout,
                                            float* __restrict__ out) {
    int g = blockIdx.x * 64 + threadIdx.x;
    if (g >= NUM_GRAPHS) return;
    float inv = 1.0f / fmaxf(counts[g], 1.0f);
    float acc = bout[0];
#pragma unroll
    for (int c = 0; c < EMB; ++c) {
        float s = sums[g * EMB + c];
        acc += s * Wout[c] + s * inv * Wout[EMB + c];
    }
    out[g] = acc;
}

extern "C" void kernel_launch(void* const* d_in, const int* in_sizes, int n_in,
                              void* d_out, int out_size, void* d_ws, size_t ws_size,
                              hipStream_t stream) {
    const float* x     = (const float*)d_in[0];
    const int*   ei    = (const int*)d_in[1];   // [2, E]
    const int*   batch = (const int*)d_in[2];   // [N], sorted
    const float* W1    = (const float*)d_in[3];
    const float* b1    = (const float*)d_in[4];
    const float* Wout  = (const float*)d_in[5];
    const float* bout  = (const float*)d_in[6];
    float* out = (float*)d_out;

    // workspace (~33 MB)
    char* ws = (char*)d_ws;
    __half* xwh        = (__half*)ws;       ws += (size_t)N_NODES * EMB * sizeof(__half);  // 6.4 MB
    unsigned int* recs = (unsigned int*)ws; ws += (size_t)N_EDGES * sizeof(int);           // 12.8 MB
    int*   edge_src    = (int*)ws;          ws += (size_t)N_EDGES * sizeof(int);           // 12.8 MB
    int*   rowstart    = (int*)ws;          ws += (size_t)(N_NODES + 4) * sizeof(int);     // 0.4 MB
    float* dinv        = (float*)ws;        ws += (size_t)N_NODES * sizeof(float);         // 0.4 MB
    int*   cbase       = (int*)ws;          ws += (FB + 2) * sizeof(int);
    float* sums        = (float*)ws;        ws += (size_t)NUM_GRAPHS * EMB * sizeof(float);
    float* counts      = (float*)ws;

    // Overlay the prefix-sum scratch inside edge_src: bhist (2 MB) + part
    // (64 KB) + bbase (2 MB) are dead before k_fill2 writes edge_src.
    int* bhist = edge_src;                       // [FB_B][FB]  2 MB
    int* part  = bhist + (size_t)FB_B * FB;      // [NCHUNK][FB] 64 KB
    int* bbase = part + (size_t)NCHUNK * FB;     // [FB_B][FB]  2 MB

    k_hist  <<<FB_B, 512, 0, stream>>>(ei, bhist);
    k_part  <<<NCHUNK + 1, 512, 0, stream>>>(bhist, part, batch, sums, counts);
    k_mid   <<<NCHUNK, 1024, 0, stream>>>(bhist, part, bbase, cbase);
    k_fill  <<<FB_B, 512, 0, stream>>>(ei, bhist, bbase, recs);
    k_fill2 <<<NBUCKETS, 512, 0, stream>>>(recs, cbase, edge_src, rowstart, dinv);
    k_xw    <<<XW_BLOCKS, 256, 0, stream>>>(x, W1, dinv, xwh);
    k_gather<<<N_NODES / 16, 256, 0, stream>>>(xwh, dinv, rowstart, edge_src, batch, b1, sums);
    k_out   <<<(NUM_GRAPHS + 63) / 64, 64, 0, stream>>>(sums, counts, Wout, bout, out);
}